// Round 1
// baseline (1062.696 us; speedup 1.0000x reference)
//
#include <hip/hip_runtime.h>
#include <math.h>

// ---- problem constants ----
constexpr int kHF = 361, kWF = 720;       // full grid
constexpr int kHP = 90,  kWP = 180;       // processor grid
constexpr int kCIN = 26, kCE = 48, kCOUT = 24;
constexpr int kK = 9, kNB = 6;
constexpr int kL = 90, kM = 90;
constexpr int kNL = 4, kHD = 96;
constexpr int kNP  = kHP * kWP;           // 16200
constexpr int kNPF = kHF * kWF;           // 259920

#ifndef M_PI
#define M_PI 3.14159265358979323846
#endif

// ---------------- precompute: DFT tables ----------------
// fwd (rfft/WP):   xf_re[m] = sum_w g[w] * cos(2pi m w/180)/180
//                  xf_im[m] = sum_w g[w] * (-sin(2pi m w/180))/180
// inv (irfft*WP):  g[w] = sum_m s_m*(re[m] cos(2pi m w/180) - im[m] sin(...)), s_0=1, s_m=2
__global__ __launch_bounds__(256) void k_tables(float* __restrict__ fc, float* __restrict__ fs,
                                                float* __restrict__ ic, float* __restrict__ isn) {
    int t = blockIdx.x * 256 + threadIdx.x;
    if (t >= kM * kWP) return;
    int m = t / kWP, w = t % kWP;
    double th = (2.0 * M_PI / (double)kWP) * (double)(m * w);
    double c = cos(th), s = sin(th);
    fc[w * kM + m] = (float)(c / (double)kWP);
    fs[w * kM + m] = (float)(-s / (double)kWP);
    float sc = (m == 0) ? 1.0f : 2.0f;
    ic[m * kWP + w] = sc * (float)c;
    isn[m * kWP + w] = sc * (float)s;
}

// transpose Legendre matrices for coalesced m-reads
// mode 0: PwT[(l*90+t)*90+m] = Pw[(l*90+m)*90+t]
// mode 1: PiT[(t*90+l)*90+m] = Pi[(l*90+m)*90+t]
__global__ __launch_bounds__(256) void k_trans(const float* __restrict__ P, float* __restrict__ PT, int mode) {
    int t = blockIdx.x * 256 + threadIdx.x;
    if (t >= kL * kM * kHP) return;
    int l = t / (kM * kHP);
    int r = t % (kM * kHP);
    int m = r / kHP;
    int tt = r % kHP;
    float v = P[t];
    if (mode == 0) PT[(l * kHP + tt) * kM + m] = v;
    else           PT[(tt * kL + l) * kM + m] = v;
}

// ---------------- disco conv (encoder / processor) ----------------
// y[o,p] = sum_{i,k} w[o,i,k] * sum_n vals[k,p,n] * src[i, idx[p,n]]
// OG output-channel groups for grid parallelism; weights read via (wave-uniform) global loads.
template <int TCIN, int TCOUT, int OG>
__global__ __launch_bounds__(256) void k_disco(const float* __restrict__ src, int srcStride,
                                               const int* __restrict__ idx, const float* __restrict__ vals,
                                               const float* __restrict__ w, float* __restrict__ out, int np) {
    int gt = blockIdx.x * 256 + threadIdx.x;
    if (gt >= np * OG) return;
    int p = gt % np;
    int og = gt / np;
    constexpr int OC = TCOUT / OG;

    int qi[kNB];
#pragma unroll
    for (int n = 0; n < kNB; n++) qi[n] = idx[p * kNB + n];

    float acc[OC];
#pragma unroll
    for (int o = 0; o < OC; o++) acc[o] = 0.0f;

    const float* wbase = w + (size_t)og * OC * TCIN * kK;

    for (int i = 0; i < TCIN; i++) {
        float xg[kNB];
#pragma unroll
        for (int n = 0; n < kNB; n++) xg[n] = src[i * srcStride + qi[n]];
        float z[kK];
#pragma unroll
        for (int k = 0; k < kK; k++) {
            const float* vp = vals + ((size_t)k * np + p) * kNB;
            float zz = 0.0f;
#pragma unroll
            for (int n = 0; n < kNB; n++) zz = fmaf(vp[n], xg[n], zz);
            z[k] = zz;
        }
#pragma unroll
        for (int o = 0; o < OC; o++) {
            const float* wp = wbase + ((size_t)o * TCIN + i) * kK;
            float s = acc[o];
#pragma unroll
            for (int k = 0; k < kK; k++) s = fmaf(wp[k], z[k], s);
            acc[o] = s;
        }
    }
#pragma unroll
    for (int o = 0; o < OC; o++) out[(size_t)(og * OC + o) * np + p] = acc[o];
}

// ---------------- spectral pipeline ----------------
// S1: rfft rows (48*90 rows of 180) -> xf (48,90,90) complex
__global__ __launch_bounds__(256) void k_rfft(const float* __restrict__ g, const float* __restrict__ fc,
                                              const float* __restrict__ fs, float* __restrict__ xre,
                                              float* __restrict__ xim) {
    int t = blockIdx.x * 256 + threadIdx.x;
    if (t >= kCE * kHP * kM) return;
    int m = t % kM;
    int row = t / kM;
    const float* gr = g + (size_t)row * kWP;
    float ar = 0.0f, ai = 0.0f;
    for (int w = 0; w < kWP; w++) {
        float gv = gr[w];
        ar = fmaf(gv, fc[w * kM + m], ar);
        ai = fmaf(gv, fs[w * kM + m], ai);
    }
    xre[t] = ar;
    xim[t] = ai;
}

// S2: c[c,l,m] = sum_t PwT[(l*90+t)*90+m] * xf[c,t,m]
__global__ __launch_bounds__(256) void k_sht(const float* __restrict__ PwT, const float* __restrict__ xre,
                                             const float* __restrict__ xim, float* __restrict__ cre,
                                             float* __restrict__ cim) {
    int t = blockIdx.x * 256 + threadIdx.x;
    if (t >= kCE * kL * kM) return;
    int m = t % kM;
    int l = (t / kM) % kL;
    int c = t / (kM * kL);
    float ar = 0.0f, ai = 0.0f;
    for (int tt = 0; tt < kHP; tt++) {
        float pv = PwT[((size_t)l * kHP + tt) * kM + m];
        ar = fmaf(pv, xre[((size_t)c * kHP + tt) * kM + m], ar);
        ai = fmaf(pv, xim[((size_t)c * kHP + tt) * kM + m], ai);
    }
    cre[t] = ar;
    cim[t] = ai;
}

// S3: c2[o,l,m] = sum_i gw[o,i,l] * c[i,l,m]
__global__ __launch_bounds__(256) void k_gmix(const float* __restrict__ gwl, const float* __restrict__ cre,
                                              const float* __restrict__ cim, float* __restrict__ ore,
                                              float* __restrict__ oim) {
    int t = blockIdx.x * 256 + threadIdx.x;
    if (t >= kCE * kL * kM) return;
    int m = t % kM;
    int l = (t / kM) % kL;
    int o = t / (kM * kL);
    float ar = 0.0f, ai = 0.0f;
    for (int i = 0; i < kCE; i++) {
        float gv = gwl[((size_t)o * kCE + i) * kL + l];
        ar = fmaf(gv, cre[((size_t)i * kL + l) * kM + m], ar);
        ai = fmaf(gv, cim[((size_t)i * kL + l) * kM + m], ai);
    }
    ore[t] = ar;
    oim[t] = ai;
}

// S4: xf2[c,t,m] = sum_l PiT[(t*90+l)*90+m] * c2[c,l,m]
__global__ __launch_bounds__(256) void k_isht(const float* __restrict__ PiT, const float* __restrict__ cre,
                                              const float* __restrict__ cim, float* __restrict__ xre,
                                              float* __restrict__ xim) {
    int t = blockIdx.x * 256 + threadIdx.x;
    if (t >= kCE * kHP * kM) return;
    int m = t % kM;
    int tt = (t / kM) % kHP;
    int c = t / (kM * kHP);
    float ar = 0.0f, ai = 0.0f;
    for (int l = 0; l < kL; l++) {
        float pv = PiT[((size_t)tt * kL + l) * kM + m];
        ar = fmaf(pv, cre[((size_t)c * kL + l) * kM + m], ar);
        ai = fmaf(pv, cim[((size_t)c * kL + l) * kM + m], ai);
    }
    xre[t] = ar;
    xim[t] = ai;
}

// S5: dx[c,t,w] = sum_m s_m*(re[c,t,m]*cos - im[c,t,m]*sin)
__global__ __launch_bounds__(256) void k_irfft(const float* __restrict__ xre, const float* __restrict__ xim,
                                               const float* __restrict__ ic, const float* __restrict__ isn,
                                               float* __restrict__ dx) {
    int t = blockIdx.x * 256 + threadIdx.x;
    if (t >= kCE * kHP * kWP) return;
    int w = t % kWP;
    int row = t / kWP;
    const float* xr = xre + (size_t)row * kM;
    const float* xi = xim + (size_t)row * kM;
    float a = 0.0f;
    for (int m = 0; m < kM; m++) {
        a = fmaf(xr[m], ic[m * kWP + w], a);
        a = fmaf(-xi[m], isn[m * kWP + w], a);
    }
    dx[t] = a;
}

// ---------------- MLP ----------------
__device__ __forceinline__ float gelu_tanh(float x) {
    float x3 = x * x * x;
    float t = tanhf(0.7978845608028654f * (x + 0.044715f * x3));
    return 0.5f * x * (1.0f + t);
}

__global__ __launch_bounds__(256) void k_mlp1(const float* __restrict__ m1w, const float* __restrict__ dx,
                                              float* __restrict__ dx1) {
    int t = blockIdx.x * 256 + threadIdx.x;
    if (t >= kHD * kNP) return;
    int p = t % kNP;
    int hh = t / kNP;
    float a = 0.0f;
    for (int i = 0; i < kCE; i++) a = fmaf(m1w[hh * kCE + i], dx[(size_t)i * kNP + p], a);
    dx1[t] = gelu_tanh(a);
}

__global__ __launch_bounds__(256) void k_mlp2(const float* __restrict__ m2w, const float* __restrict__ lsw,
                                              const float* __restrict__ dx1, float* __restrict__ h) {
    int t = blockIdx.x * 256 + threadIdx.x;
    if (t >= kCE * kNP) return;
    int p = t % kNP;
    int o = t / kNP;
    float a = 0.0f;
    for (int j = 0; j < kHD; j++) a = fmaf(m2w[o * kHD + j], dx1[(size_t)j * kNP + p], a);
    h[t] = h[t] + lsw[o] * a;
}

// ---------------- decoder: fused bilinear upsample + disco conv ----------------
__global__ __launch_bounds__(256) void k_dec(const float* __restrict__ h, const int* __restrict__ didx,
                                             const float* __restrict__ dvals, const float* __restrict__ dw,
                                             const int* __restrict__ li0, const int* __restrict__ li1,
                                             const float* __restrict__ lwt, const int* __restrict__ oi0,
                                             const int* __restrict__ oi1, const float* __restrict__ owt,
                                             float* __restrict__ out) {
    __shared__ float wl[kCOUT * kCE * kK];  // 10368 floats = 41.5 KB
    for (int t = threadIdx.x; t < kCOUT * kCE * kK; t += 256) wl[t] = dw[t];
    __syncthreads();

    int p = blockIdx.x * 256 + threadIdx.x;
    if (p >= kNPF) return;

    int b0[kNB], b1[kNB], b2[kNB], b3[kNB];
    float w0[kNB], w1[kNB], w2[kNB], w3[kNB];
#pragma unroll
    for (int n = 0; n < kNB; n++) {
        int q = didx[p * kNB + n];
        int qa = q / kWF;
        int qo = q - qa * kWF;
        int a0 = li0[qa], a1 = li1[qa];
        float aw = lwt[qa];
        int o0 = oi0[qo], o1 = oi1[qo];
        float ow = owt[qo];
        b0[n] = a0 * kWP + o0; w0[n] = (1.0f - aw) * (1.0f - ow);
        b1[n] = a0 * kWP + o1; w1[n] = (1.0f - aw) * ow;
        b2[n] = a1 * kWP + o0; w2[n] = aw * (1.0f - ow);
        b3[n] = a1 * kWP + o1; w3[n] = aw * ow;
    }

    float acc[kCOUT];
#pragma unroll
    for (int o = 0; o < kCOUT; o++) acc[o] = 0.0f;

    for (int i = 0; i < kCE; i++) {
        const float* hi = h + (size_t)i * kNP;
        float xg[kNB];
#pragma unroll
        for (int n = 0; n < kNB; n++) {
            xg[n] = hi[b0[n]] * w0[n] + hi[b1[n]] * w1[n] + hi[b2[n]] * w2[n] + hi[b3[n]] * w3[n];
        }
        float z[kK];
#pragma unroll
        for (int k = 0; k < kK; k++) {
            const float* vp = dvals + ((size_t)k * kNPF + p) * kNB;
            float zz = 0.0f;
#pragma unroll
            for (int n = 0; n < kNB; n++) zz = fmaf(vp[n], xg[n], zz);
            z[k] = zz;
        }
#pragma unroll
        for (int o = 0; o < kCOUT; o++) {
            const float* wp = &wl[(o * kCE + i) * kK];
            float s = acc[o];
#pragma unroll
            for (int k = 0; k < kK; k++) s = fmaf(wp[k], z[k], s);
            acc[o] = s;
        }
    }
#pragma unroll
    for (int o = 0; o < kCOUT; o++) out[(size_t)o * kNPF + p] = acc[o];
}

// ---------------- host launcher ----------------
extern "C" void kernel_launch(void* const* d_in, const int* in_sizes, int n_in,
                              void* d_out, int out_size, void* d_ws, size_t ws_size,
                              hipStream_t stream) {
    const float* x         = (const float*)d_in[0];
    const int*   enc_idx   = (const int*)d_in[1];
    const float* enc_vals  = (const float*)d_in[2];
    const float* enc_w     = (const float*)d_in[3];
    const int*   proc_idx  = (const int*)d_in[4];
    const float* proc_vals = (const float*)d_in[5];
    const float* lw        = (const float*)d_in[6];
    const float* gw        = (const float*)d_in[7];
    const float* Pw        = (const float*)d_in[8];
    const float* Pi        = (const float*)d_in[9];
    const float* m1        = (const float*)d_in[10];
    const float* m2        = (const float*)d_in[11];
    const float* ls        = (const float*)d_in[12];
    const int*   li0       = (const int*)d_in[13];
    const int*   li1       = (const int*)d_in[14];
    const float* lwt       = (const float*)d_in[15];
    const int*   oi0       = (const int*)d_in[16];
    const int*   oi1       = (const int*)d_in[17];
    const float* owt       = (const float*)d_in[18];
    const int*   dec_idx   = (const int*)d_in[19];
    const float* dec_vals  = (const float*)d_in[20];
    const float* dec_w     = (const float*)d_in[21];
    float* out = (float*)d_out;

    // workspace layout (floats); total ~28 MB
    float* ws = (float*)d_ws;
    size_t off = 0;
    auto alloc = [&](size_t n) { float* p = ws + off; off += n; return p; };
    float* h    = alloc((size_t)kCE * kNP);        // 777600
    float* xre  = alloc((size_t)kCE * kHP * kM);   // 388800
    float* xim  = alloc((size_t)kCE * kHP * kM);
    float* cre  = alloc((size_t)kCE * kL * kM);
    float* cim  = alloc((size_t)kCE * kL * kM);
    float* c2re = alloc((size_t)kCE * kL * kM);
    float* c2im = alloc((size_t)kCE * kL * kM);
    float* dx   = alloc((size_t)kCE * kNP);        // 777600
    float* dx1  = alloc((size_t)kHD * kNP);        // 1555200
    float* fc   = alloc((size_t)kM * kWP);
    float* fs   = alloc((size_t)kM * kWP);
    float* ic   = alloc((size_t)kM * kWP);
    float* isn  = alloc((size_t)kM * kWP);
    float* PwT  = alloc((size_t)kL * kM * kHP);    // 729000
    float* PiT  = alloc((size_t)kL * kM * kHP);
    (void)ws_size; (void)in_sizes; (void)n_in; (void)out_size;

    dim3 B(256);
    auto nb = [](long long n) { return dim3((unsigned)((n + 255) / 256)); };

    k_tables<<<nb(kM * kWP), B, 0, stream>>>(fc, fs, ic, isn);
    k_trans<<<nb((long long)kL * kM * kHP), B, 0, stream>>>(Pw, PwT, 0);
    k_trans<<<nb((long long)kL * kM * kHP), B, 0, stream>>>(Pi, PiT, 1);

    // encoder
    k_disco<kCIN, kCE, 4><<<nb((long long)kNP * 4), B, 0, stream>>>(
        x, kNPF, enc_idx, enc_vals, enc_w, h, kNP);

    for (int i = 0; i < kNL; i++) {
        if (i % 2 == 0) {
            const float* gwl = gw + (size_t)(i / 2) * kCE * kCE * kL;
            k_rfft<<<nb((long long)kCE * kHP * kM), B, 0, stream>>>(h, fc, fs, xre, xim);
            k_sht<<<nb((long long)kCE * kL * kM), B, 0, stream>>>(PwT, xre, xim, cre, cim);
            k_gmix<<<nb((long long)kCE * kL * kM), B, 0, stream>>>(gwl, cre, cim, c2re, c2im);
            k_isht<<<nb((long long)kCE * kHP * kM), B, 0, stream>>>(PiT, c2re, c2im, xre, xim);
            k_irfft<<<nb((long long)kCE * kHP * kWP), B, 0, stream>>>(xre, xim, ic, isn, dx);
        } else {
            const float* lwl = lw + (size_t)(i / 2) * kCE * kCE * kK;
            k_disco<kCE, kCE, 4><<<nb((long long)kNP * 4), B, 0, stream>>>(
                h, kNP, proc_idx, proc_vals, lwl, dx, kNP);
        }
        k_mlp1<<<nb((long long)kHD * kNP), B, 0, stream>>>(m1 + (size_t)i * kHD * kCE, dx, dx1);
        k_mlp2<<<nb((long long)kCE * kNP), B, 0, stream>>>(m2 + (size_t)i * kCE * kHD, ls + (size_t)i * kCE, dx1, h);
    }

    // decoder: fused bilinear upsample + disco conv
    k_dec<<<nb((long long)kNPF), B, 0, stream>>>(h, dec_idx, dec_vals, dec_w,
                                                 li0, li1, lwt, oi0, oi1, owt, out);
}